// Round 7
// baseline (199.031 us; speedup 1.0000x reference)
//
#include <hip/hip_runtime.h>
#include <cstdint>
#include <cstddef>

// Problem constants (B=8, C=512, H=W=64, HEAD_DIM=64, PS=2)
#define T_TOK  2048   // k_sel * ps*ps tokens per (b,head)
#define NPATCH 1024
#define KSEL   512
#define BH_N   64     // B * nh

typedef unsigned short u16;
typedef __attribute__((ext_vector_type(8))) short bf16x8;   // MFMA A/B frag (4 VGPR)
typedef __attribute__((ext_vector_type(4))) float f32x4;
typedef __attribute__((ext_vector_type(16))) float f32x16;  // 32x32 MFMA C/D frag

// Workspace layout (bytes). Total = ~80.3 MiB
#define WS_Q   ((size_t)0)            // bf16 [64][2048][64]  Q (pre-scaled by 0.125*log2e)
#define WS_K   ((size_t)16 << 20)     // bf16 [64][2048][64]
#define WS_VT  ((size_t)32 << 20)     // bf16 [64][64][2048]  V transposed
#define WS_OT  ((size_t)48 << 20)     // f32  [64][2048][64]  out tokens (t-major); first 16MiB double as tok buffer
#define WS_INV ((size_t)80 << 20)     // i32  [64][1024]

static __device__ __forceinline__ u16 f2bf(float f){
  union { float f; unsigned u; } un; un.f = f;
  return (u16)((un.u + 0x7FFFu + ((un.u >> 16) & 1u)) >> 16);  // RNE
}

static __device__ __forceinline__ void gload16(const void* g, void* l){
  __builtin_amdgcn_global_load_lds(
      (const __attribute__((address_space(1))) void*)g,
      (__attribute__((address_space(3))) void*)l, 16, 0, 0);
}

// ---- inverse patch map: inv[bh][p] = selected index kk, or -1 ------------
__global__ __launch_bounds__(512)
void k_inv(const int* __restrict__ topk, int* __restrict__ inv){
  inv[blockIdx.x*NPATCH + topk[blockIdx.x*KSEL + threadIdx.x]] = threadIdx.x;
}

// ---- token build: dense layout-order read of x, write selected tokens ----
__global__ __launch_bounds__(256)
void k_tok(const float* __restrict__ x, const int* __restrict__ inv,
           u16* __restrict__ tok){
  __shared__ u16 tile[64][132];   // [d][pix]
  __shared__ int invs[32];
  const int tid = threadIdx.x;
  const int pr = blockIdx.x, bh = blockIdx.y;
  const int b = bh >> 3, h = bh & 7;
  if (tid < 32) invs[tid] = inv[bh*NPATCH + pr*32 + tid];
  const float* xb = x + ((size_t)(b*512 + h*64)*64 + 2*pr)*64;
  #pragma unroll
  for (int i = 0; i < 8; ++i){
    const int f = i*1024 + tid*4;
    const int d = f >> 7, y = (f >> 6) & 1, xx = f & 63;
    float4 v = *(const float4*)(xb + ((size_t)d*64 + y)*64 + xx);
    unsigned lo, hi;
    asm("v_cvt_pk_bf16_f32 %0, %1, %2" : "=v"(lo) : "v"(v.x), "v"(v.y));
    asm("v_cvt_pk_bf16_f32 %0, %1, %2" : "=v"(hi) : "v"(v.z), "v"(v.w));
    uint2 pk2; pk2.x = lo; pk2.y = hi;
    *(uint2*)&tile[d][y*64 + xx] = pk2;
  }
  __syncthreads();
  const int p = tid >> 3, j = tid & 7;
  const int kk = invs[p];
  if (kk >= 0){
    u16* dst = tok + ((size_t)bh*T_TOK + kk*4)*64;
    #pragma unroll
    for (int i = 0; i < 4; ++i){
      const int chunk = j*4 + i;
      const int quad = chunk >> 3, d16 = (chunk & 7)*8;
      const int pix = (quad >> 1)*64 + p*2 + (quad & 1);
      union { u16 s[8]; uint4 q; } un;
      #pragma unroll
      for (int k2 = 0; k2 < 8; ++k2) un.s[k2] = tile[d16 + k2][pix];
      *(uint4*)(dst + quad*64 + d16) = un.q;
    }
  }
}

// ---- QKV GEMM: tokens (coalesced) x W(192x64) -> Q(pre-scaled),K,Vt ------
__global__ __launch_bounds__(256)
void k_qkv(const u16* __restrict__ tok, const float* __restrict__ w,
           const float* __restrict__ bias,
           u16* __restrict__ Q, u16* __restrict__ K, u16* __restrict__ Vt){
  __shared__ u16 Wl[192][72];
  __shared__ float biasl[192];
  const int tid = threadIdx.x;
  const int chunk = blockIdx.x;
  const int bh = blockIdx.y;
  for (int i2 = tid; i2 < 192*64; i2 += 256) Wl[i2 >> 6][i2 & 63] = f2bf(w[i2]);
  if (tid < 192) biasl[tid] = bias[tid];
  __syncthreads();

  const int lane = tid & 63, wv = tid >> 6;
  const int c = lane & 15, g = lane >> 4;
  const float QSC = 0.18033688f;   // 0.125 * log2(e)
  for (int tile = 0; tile < 4; ++tile){
    const int t0 = chunk*256 + tile*64;
    const int trow = t0 + wv*16 + c;
    const u16* tr = tok + ((size_t)bh*T_TOK + trow)*64;
    const bf16x8 a0 = *(const bf16x8*)(tr + 8*g);
    const bf16x8 a1 = *(const bf16x8*)(tr + 32 + 8*g);
    const int orow = t0 + wv*16 + 4*g;
    #pragma unroll
    for (int nf = 0; nf < 12; ++nf){
      const int e = nf*16 + c;
      const bf16x8 b0 = *(const bf16x8*)&Wl[e][8*g];
      const bf16x8 b1 = *(const bf16x8*)&Wl[e][32 + 8*g];
      f32x4 acc = {0.f, 0.f, 0.f, 0.f};
      acc = __builtin_amdgcn_mfma_f32_16x16x32_bf16(a0, b0, acc, 0, 0, 0);
      acc = __builtin_amdgcn_mfma_f32_16x16x32_bf16(a1, b1, acc, 0, 0, 0);
      const float bb = biasl[e];
      if (e < 64){
        u16* dst = Q + ((size_t)bh*T_TOK + orow)*64 + e;
        #pragma unroll
        for (int r2 = 0; r2 < 4; ++r2) dst[(size_t)r2*64] = f2bf((acc[r2] + bb)*QSC);
      } else if (e < 128){
        u16* dst = K + ((size_t)bh*T_TOK + orow)*64 + (e - 64);
        #pragma unroll
        for (int r2 = 0; r2 < 4; ++r2) dst[(size_t)r2*64] = f2bf(acc[r2] + bb);
      } else {
        u16* dst = Vt + ((size_t)bh*64 + (e - 128))*T_TOK + orow;
        unsigned u01 = (unsigned)f2bf(acc[0] + bb) | ((unsigned)f2bf(acc[1] + bb) << 16);
        unsigned u23 = (unsigned)f2bf(acc[2] + bb) | ((unsigned)f2bf(acc[3] + bb) << 16);
        *(unsigned*)(dst)     = u01;
        *(unsigned*)(dst + 2) = u23;
      }
    }
  }
}

// ---- flash attention: 4 waves x 32 q-rows, 4 blocks/CU -------------------
// K: global_load_lds DMA into XOR-swizzled LDS (pre-swizzled source, T21).
// V: B-fragments loaded directly from global (L2-resident), no LDS.
// No-max softmax (exact: Q pre-scaled by 0.125*log2e, logits tiny).
__global__ __launch_bounds__(256, 4)
void k_attn(const u16* __restrict__ Q, const u16* __restrict__ K,
            const u16* __restrict__ Vt, float* __restrict__ OT){
  __shared__ u16 Kl[2][4096];   // [key][d] 64 rows x 128B, chunk ^= (row&7)
  const int tid = threadIdx.x;
  const int bh = blockIdx.x, qt = blockIdx.y;   // bh-major: qt blocks share one XCD's L2
  const int l = tid & 63, w = tid >> 6;
  const int h = l >> 5, c31 = l & 31, l7 = l & 7;
  const int qbase = qt*128 + w*32;

  // Q fragments (B-operand)
  bf16x8 qf[4];
  {
    const u16* qr = Q + ((size_t)bh*T_TOK + qbase + c31)*64;
    #pragma unroll
    for (int kd = 0; kd < 4; ++kd) qf[kd] = *(const bf16x8*)(qr + kd*16 + 8*h);
  }

  // K DMA source: LDS linear pos tid*16 (+4096) <- global chunk pre-swizzled
  const u16* Kg = K + (size_t)bh*T_TOK*64;
  const int srow = tid >> 3, schunk = tid & 7;
  const u16* gK0 = Kg + srow*64 + (schunk ^ (srow & 7))*8;   // shot1 = +2048

  // V per-lane fragment base: Vt[bh][d = c31 (+32)][t], 8 u16 per frag
  const u16* gV0 = Vt + (size_t)bh*64*T_TOK + (size_t)c31*T_TOK + 8*h;

  // hoisted K frag offsets (u16 units): row c31(+32), chunk (2ds+h)^(row&7)
  int fcol[4];
  #pragma unroll
  for (int ds = 0; ds < 4; ++ds)
    fcol[ds] = c31*64 + (((32*ds + 16*h) ^ (16*l7)) >> 1);

  f32x16 accO[2];
  #pragma unroll
  for (int i = 0; i < 2; ++i)
    #pragma unroll
    for (int r = 0; r < 16; ++r) accO[i][r] = 0.f;
  float ls = 0.f;

  // prologue: stage K tile 0 into buffer 0
  gload16(gK0,        &Kl[0][w*512]);
  gload16(gK0 + 2048, &Kl[0][w*512 + 2048]);
  __syncthreads();

  int cur = 0;
  for (int kt = 0; kt < 32; ++kt){
    // issue next K tile DMA (lands before the end-of-iter barrier)
    if (kt < 31){
      const u16* sp = gK0 + (kt + 1)*4096;
      u16* dp = &Kl[cur ^ 1][w*512];
      gload16(sp,        dp);
      gload16(sp + 2048, dp + 2048);
    }

    // ---- S^T = K Q^T (rows = keys, cols = q) ----
    f32x16 s0, s1;
    #pragma unroll
    for (int r = 0; r < 16; ++r){ s0[r] = 0.f; s1[r] = 0.f; }
    const u16* kb = &Kl[cur][0];
    __builtin_amdgcn_s_setprio(1);
    #pragma unroll
    for (int ds = 0; ds < 4; ++ds){
      const bf16x8 kf0 = *(const bf16x8*)(kb + fcol[ds]);
      const bf16x8 kf1 = *(const bf16x8*)(kb + fcol[ds] + 2048);
      s0 = __builtin_amdgcn_mfma_f32_32x32x16_bf16(kf0, qf[ds], s0, 0, 0, 0);
      s1 = __builtin_amdgcn_mfma_f32_32x32x16_bf16(kf1, qf[ds], s1, 0, 0, 0);
    }
    __builtin_amdgcn_s_setprio(0);

    // ---- V frags ks=0,1 from global (latency hides under softmax) ----
    const u16* vb = gV0 + kt*64;
    bf16x8 vfa[4];
    vfa[0] = *(const bf16x8*)(vb);
    vfa[1] = *(const bf16x8*)(vb + (size_t)32*T_TOK);
    vfa[2] = *(const bf16x8*)(vb + 16);
    vfa[3] = *(const bf16x8*)(vb + (size_t)32*T_TOK + 16);

    // ---- P = exp2(S); row-sum (lane-local + cross-half) ----
    float rs = 0.f;
    #pragma unroll
    for (int r = 0; r < 16; ++r){
      s0[r] = __builtin_amdgcn_exp2f(s0[r]);
      s1[r] = __builtin_amdgcn_exp2f(s1[r]);
      rs += s0[r] + s1[r];
    }
    rs += __shfl_xor(rs, 32);
    ls += rs;

    // ---- pack to bf16, build PV A-frags via permlane32_swap ----
    unsigned pk[16];
    #pragma unroll
    for (int i = 0; i < 8; ++i){
      asm("v_cvt_pk_bf16_f32 %0, %1, %2" : "=v"(pk[i])   : "v"(s0[2*i]), "v"(s0[2*i+1]));
      asm("v_cvt_pk_bf16_f32 %0, %1, %2" : "=v"(pk[8+i]) : "v"(s1[2*i]), "v"(s1[2*i+1]));
    }
    bf16x8 paf[4];
    #pragma unroll
    for (int ks = 0; ks < 4; ++ks){
      const int J = 8*(ks >> 1) + 4*(ks & 1);
      unsigned a0 = pk[J+0], b0 = pk[J+2];
      unsigned a1 = pk[J+1], b1 = pk[J+3];
      asm("v_permlane32_swap_b32 %0, %1" : "+v"(a0), "+v"(b0));
      asm("v_permlane32_swap_b32 %0, %1" : "+v"(a1), "+v"(b1));
      union { unsigned u[4]; bf16x8 v; } un;
      un.u[0] = a0; un.u[1] = a1; un.u[2] = b0; un.u[3] = b1;
      paf[ks] = un.v;
    }

    // ---- V frags ks=2,3 (latency hides under first PV half) ----
    bf16x8 vfb[4];
    vfb[0] = *(const bf16x8*)(vb + 32);
    vfb[1] = *(const bf16x8*)(vb + (size_t)32*T_TOK + 32);
    vfb[2] = *(const bf16x8*)(vb + 48);
    vfb[3] = *(const bf16x8*)(vb + (size_t)32*T_TOK + 48);

    // ---- O += P V ----
    __builtin_amdgcn_s_setprio(1);
    accO[0] = __builtin_amdgcn_mfma_f32_32x32x16_bf16(paf[0], vfa[0], accO[0], 0, 0, 0);
    accO[1] = __builtin_amdgcn_mfma_f32_32x32x16_bf16(paf[0], vfa[1], accO[1], 0, 0, 0);
    accO[0] = __builtin_amdgcn_mfma_f32_32x32x16_bf16(paf[1], vfa[2], accO[0], 0, 0, 0);
    accO[1] = __builtin_amdgcn_mfma_f32_32x32x16_bf16(paf[1], vfa[3], accO[1], 0, 0, 0);
    accO[0] = __builtin_amdgcn_mfma_f32_32x32x16_bf16(paf[2], vfb[0], accO[0], 0, 0, 0);
    accO[1] = __builtin_amdgcn_mfma_f32_32x32x16_bf16(paf[2], vfb[1], accO[1], 0, 0, 0);
    accO[0] = __builtin_amdgcn_mfma_f32_32x32x16_bf16(paf[3], vfb[2], accO[0], 0, 0, 0);
    accO[1] = __builtin_amdgcn_mfma_f32_32x32x16_bf16(paf[3], vfb[3], accO[1], 0, 0, 0);
    __builtin_amdgcn_s_setprio(0);

    __syncthreads();   // drains next-tile DMA (vmcnt) + protects buffer swap
    cur ^= 1;
  }

  // ---- epilogue: normalize, direct stores to OT[bh][t][d] ------
  const float rl = 1.0f / ls;
  #pragma unroll
  for (int r = 0; r < 16; ++r){
    const int qr = (r & 3) + 8*(r >> 2) + 4*h;
    const float sa = __uint_as_float(
        (unsigned)__builtin_amdgcn_ds_bpermute(qr << 2, (int)__float_as_uint(rl)));
    float* dst = OT + ((size_t)bh*T_TOK + qbase + qr)*64;
    dst[c31]      = accO[0][r]*sa;
    dst[32 + c31] = accO[1][r]*sa;
  }
}

// ---- emit: both-sides-coalesced via LDS transpose ------------------------
__global__ __launch_bounds__(256)
void k_emit(const float* __restrict__ OT, const int* __restrict__ inv,
            float* __restrict__ out){
  __shared__ float obuf[128][68];   // [pix = y*64+x][d], pad 4
  __shared__ int invs[32];
  const int tid = threadIdx.x;
  const int pr = blockIdx.x, bh = blockIdx.y;
  const int b = bh >> 3, h = bh & 7;
  if (tid < 32) invs[tid] = inv[bh*NPATCH + pr*32 + tid];
  __syncthreads();
  const int g = tid >> 3, j = tid & 7;
  const int kk = invs[g];
  const float* tbase = OT + ((size_t)bh*T_TOK + 4*kk)*64 + j*8;
  #pragma unroll
  for (int quad = 0; quad < 4; ++quad){
    float4 v0 = {0.f,0.f,0.f,0.f}, v1 = {0.f,0.f,0.f,0.f};
    if (kk >= 0){
      v0 = *(const float4*)(tbase + quad*64);
      v1 = *(const float4*)(tbase + quad*64 + 4);
    }
    const int pix = (quad >> 1)*64 + g*2 + (quad & 1);
    *(float4*)&obuf[pix][j*8]     = v0;
    *(float4*)&obuf[pix][j*8 + 4] = v1;
  }
  __syncthreads();
  float* ob = out + ((size_t)(b*512 + h*64)*64 + 2*pr)*64;
  #pragma unroll
  for (int it = 0; it < 8; ++it){
    const int rid = it*16 + (tid >> 4);      // d*2 + y
    const int d = rid >> 1, y = rid & 1;
    const int x0 = (tid & 15)*4;
    float4 o;
    o.x = obuf[y*64 + x0 + 0][d];
    o.y = obuf[y*64 + x0 + 1][d];
    o.z = obuf[y*64 + x0 + 2][d];
    o.w = obuf[y*64 + x0 + 3][d];
    *(float4*)(ob + ((size_t)d*64 + y)*64 + x0) = o;
  }
}

extern "C" void kernel_launch(void* const* d_in, const int* in_sizes, int n_in,
                              void* d_out, int out_size, void* d_ws, size_t ws_size,
                              hipStream_t stream){
  const float* x    = (const float*)d_in[0];
  const int*   topk = (const int*)  d_in[1];
  const float* w    = (const float*)d_in[2];
  const float* bias = (const float*)d_in[3];
  float* out = (float*)d_out;
  char* ws = (char*)d_ws;

  u16*   Q   = (u16*)  (ws + WS_Q);
  u16*   K   = (u16*)  (ws + WS_K);
  u16*   Vt  = (u16*)  (ws + WS_VT);
  float* OT  = (float*)(ws + WS_OT);
  u16*   tok = (u16*)  (ws + WS_OT);   // aliases OT; dead before k_attn writes
  int*   inv = (int*)  (ws + WS_INV);

  hipMemsetAsync(inv, 0xFF, BH_N*NPATCH*sizeof(int), stream);
  k_inv <<<BH_N, 512, 0, stream>>>(topk, inv);
  k_tok <<<dim3(32, BH_N), 256, 0, stream>>>(x, inv, tok);
  k_qkv <<<dim3(8, BH_N), 256, 0, stream>>>(tok, w, bias, Q, K, Vt);
  k_attn<<<dim3(BH_N, 16), 256, 0, stream>>>(Q, K, Vt, OT);
  k_emit<<<dim3(32, BH_N), 256, 0, stream>>>(OT, inv, out);
}

// Round 8
// 176.012 us; speedup vs baseline: 1.1308x; 1.1308x over previous
//
#include <hip/hip_runtime.h>
#include <cstdint>
#include <cstddef>

// Problem constants (B=8, C=512, H=W=64, HEAD_DIM=64, PS=2)
#define T_TOK  2048   // k_sel * ps*ps tokens per (b,head)
#define NPATCH 1024
#define KSEL   512
#define BH_N   64     // B * nh

typedef unsigned short u16;
typedef __attribute__((ext_vector_type(8))) short bf16x8;   // MFMA A/B frag (4 VGPR)
typedef __attribute__((ext_vector_type(4))) float f32x4;
typedef __attribute__((ext_vector_type(16))) float f32x16;  // 32x32 MFMA C/D frag

// Workspace layout (bytes). Total = ~80.3 MiB
#define WS_Q   ((size_t)0)            // bf16 [64][2048][64]  Q (pre-scaled by 0.125*log2e)
#define WS_K   ((size_t)16 << 20)     // bf16 [64][2048][64]
#define WS_VT  ((size_t)32 << 20)     // bf16 Vp[64][32kt][4ks][2C][64lane][8] (fragment-major V)
#define WS_OT  ((size_t)48 << 20)     // f32  [64][2048][64]  out tokens (t-major); first 16MiB double as tok buffer
#define WS_INV ((size_t)80 << 20)     // i32  [64][1024]

static __device__ __forceinline__ u16 f2bf(float f){
  union { float f; unsigned u; } un; un.f = f;
  return (u16)((un.u + 0x7FFFu + ((un.u >> 16) & 1u)) >> 16);  // RNE
}

// ---- inverse patch map: inv[bh][p] = selected index kk, or -1 ------------
__global__ __launch_bounds__(512)
void k_inv(const int* __restrict__ topk, int* __restrict__ inv){
  inv[blockIdx.x*NPATCH + topk[blockIdx.x*KSEL + threadIdx.x]] = threadIdx.x;
}

// ---- token build: dense layout-order read of x, write selected tokens ----
__global__ __launch_bounds__(256)
void k_tok(const float* __restrict__ x, const int* __restrict__ inv,
           u16* __restrict__ tok){
  __shared__ u16 tile[64][132];   // [d][pix]
  __shared__ int invs[32];
  const int tid = threadIdx.x;
  const int pr = blockIdx.x, bh = blockIdx.y;
  const int b = bh >> 3, h = bh & 7;
  if (tid < 32) invs[tid] = inv[bh*NPATCH + pr*32 + tid];
  const float* xb = x + ((size_t)(b*512 + h*64)*64 + 2*pr)*64;
  #pragma unroll
  for (int i = 0; i < 8; ++i){
    const int f = i*1024 + tid*4;
    const int d = f >> 7, y = (f >> 6) & 1, xx = f & 63;
    float4 v = *(const float4*)(xb + ((size_t)d*64 + y)*64 + xx);
    unsigned lo, hi;
    asm("v_cvt_pk_bf16_f32 %0, %1, %2" : "=v"(lo) : "v"(v.x), "v"(v.y));
    asm("v_cvt_pk_bf16_f32 %0, %1, %2" : "=v"(hi) : "v"(v.z), "v"(v.w));
    uint2 pk2; pk2.x = lo; pk2.y = hi;
    *(uint2*)&tile[d][y*64 + xx] = pk2;
  }
  __syncthreads();
  const int p = tid >> 3, j = tid & 7;
  const int kk = invs[p];
  if (kk >= 0){
    u16* dst = tok + ((size_t)bh*T_TOK + kk*4)*64;
    #pragma unroll
    for (int i = 0; i < 4; ++i){
      const int chunk = j*4 + i;
      const int quad = chunk >> 3, d16 = (chunk & 7)*8;
      const int pix = (quad >> 1)*64 + p*2 + (quad & 1);
      union { u16 s[8]; uint4 q; } un;
      #pragma unroll
      for (int k2 = 0; k2 < 8; ++k2) un.s[k2] = tile[d16 + k2][pix];
      *(uint4*)(dst + quad*64 + d16) = un.q;
    }
  }
}

// ---- QKV GEMM: tokens (coalesced) x W(192x64) -> Q(pre-scaled),K,Vp ------
__global__ __launch_bounds__(256)
void k_qkv(const u16* __restrict__ tok, const float* __restrict__ w,
           const float* __restrict__ bias,
           u16* __restrict__ Q, u16* __restrict__ K, u16* __restrict__ Vp){
  __shared__ u16 Wl[192][72];
  __shared__ float biasl[192];
  const int tid = threadIdx.x;
  const int chunk = blockIdx.x;
  const int bh = blockIdx.y;
  for (int i2 = tid; i2 < 192*64; i2 += 256) Wl[i2 >> 6][i2 & 63] = f2bf(w[i2]);
  if (tid < 192) biasl[tid] = bias[tid];
  __syncthreads();

  const int lane = tid & 63, wv = tid >> 6;
  const int c = lane & 15, g = lane >> 4;
  const float QSC = 0.18033688f;   // 0.125 * log2(e)
  for (int tile = 0; tile < 4; ++tile){
    const int t0 = chunk*256 + tile*64;
    const int trow = t0 + wv*16 + c;
    const u16* tr = tok + ((size_t)bh*T_TOK + trow)*64;
    const bf16x8 a0 = *(const bf16x8*)(tr + 8*g);
    const bf16x8 a1 = *(const bf16x8*)(tr + 32 + 8*g);
    const int orow = t0 + wv*16 + 4*g;
    #pragma unroll
    for (int nf = 0; nf < 12; ++nf){
      const int e = nf*16 + c;
      const bf16x8 b0 = *(const bf16x8*)&Wl[e][8*g];
      const bf16x8 b1 = *(const bf16x8*)&Wl[e][32 + 8*g];
      f32x4 acc = {0.f, 0.f, 0.f, 0.f};
      acc = __builtin_amdgcn_mfma_f32_16x16x32_bf16(a0, b0, acc, 0, 0, 0);
      acc = __builtin_amdgcn_mfma_f32_16x16x32_bf16(a1, b1, acc, 0, 0, 0);
      const float bb = biasl[e];
      if (e < 64){
        u16* dst = Q + ((size_t)bh*T_TOK + orow)*64 + e;
        #pragma unroll
        for (int r2 = 0; r2 < 4; ++r2) dst[(size_t)r2*64] = f2bf((acc[r2] + bb)*QSC);
      } else if (e < 128){
        u16* dst = K + ((size_t)bh*T_TOK + orow)*64 + (e - 64);
        #pragma unroll
        for (int r2 = 0; r2 < 4; ++r2) dst[(size_t)r2*64] = f2bf(acc[r2] + bb);
      } else {
        // fragment-major V: Vp[bh][kt][ks][C][lane=h2*32+d'][j]
        const int d  = e - 128;
        const int C  = d >> 5, dp = d & 31;
        const int kt = orow >> 6, key = orow & 63;
        const int ks = key >> 4, h2 = (key >> 3) & 1, j0 = key & 7; // j0 in {0,4}
        u16* dst = Vp + ((((size_t)bh*128 + kt*4 + ks)*2 + C)*64 + (h2*32 + dp))*8 + j0;
        unsigned u01 = (unsigned)f2bf(acc[0] + bb) | ((unsigned)f2bf(acc[1] + bb) << 16);
        unsigned u23 = (unsigned)f2bf(acc[2] + bb) | ((unsigned)f2bf(acc[3] + bb) << 16);
        *(unsigned*)(dst)     = u01;
        *(unsigned*)(dst + 2) = u23;
      }
    }
  }
}

// ---- flash attention: 4 waves x 32 q-rows, 4 blocks/CU -------------------
// K: reg-staged into XOR-swizzled LDS (shared by 4 waves).
// V: fragment-major global reads (fully coalesced 1KB/instr, L1-broadcast).
// No-max softmax (exact: Q pre-scaled by 0.125*log2e, logits tiny).
__global__ __launch_bounds__(256, 4)
void k_attn(const u16* __restrict__ Q, const u16* __restrict__ K,
            const u16* __restrict__ Vp, float* __restrict__ OT){
  __shared__ u16 Kl[2][4096];   // [key][d] 64 rows x 128B, chunk ^= (row&7)
  const int tid = threadIdx.x;
  const int bh = blockIdx.x, qt = blockIdx.y;   // bh-major: qt blocks share one XCD's L2
  const int l = tid & 63, w = tid >> 6;
  const int h = l >> 5, c31 = l & 31, l7 = l & 7;
  const int qbase = qt*128 + w*32;

  // Q fragments (B-operand)
  bf16x8 qf[4];
  {
    const u16* qr = Q + ((size_t)bh*T_TOK + qbase + c31)*64;
    #pragma unroll
    for (int kd = 0; kd < 4; ++kd) qf[kd] = *(const bf16x8*)(qr + kd*16 + 8*h);
  }

  f32x16 Z;
  #pragma unroll
  for (int r = 0; r < 16; ++r) Z[r] = 0.f;
  f32x16 accO0 = Z, accO1 = Z;
  float ls = 0.f;

  // K staging (reg -> LDS), XOR-swizzled dest
  const int rA = tid >> 3, sA = tid & 7;
  const int rB = rA + 32;
  const int offA = rA*64 + (sA ^ (rA & 7))*8;
  const int offB = rB*64 + (sA ^ (rB & 7))*8;
  const u16* Kg  = K + (size_t)bh*T_TOK*64;
  const u16* gKA = Kg + rA*64 + sA*8;
  const u16* gKB = Kg + rB*64 + sA*8;
  uint4 stK0 = *(const uint4*)gKA, stK1 = *(const uint4*)gKB;

  // V fragment base: per-lane contiguous (lane*16B within 1KB chunk)
  const u16* gVp = Vp + (size_t)bh*131072 + l*8;

  // hoisted K frag column offsets (u16 units)
  int fcol[4];
  #pragma unroll
  for (int ds = 0; ds < 4; ++ds)
    fcol[ds] = c31*64 + (((32*ds + 16*h) ^ (16*l7)) >> 1);

  int cur = 0;
  for (int kt = 0; kt < 32; ++kt){
    *(uint4*)&Kl[cur][offA] = stK0;
    *(uint4*)&Kl[cur][offB] = stK1;
    __syncthreads();

    // V frags for CURRENT tile (issued first: pre-PV vmcnt won't wait on stK)
    const u16* vt2 = gVp + kt*4096;
    bf16x8 vf[8];
    #pragma unroll
    for (int i = 0; i < 8; ++i) vf[i] = *(const bf16x8*)(vt2 + i*512);

    if (kt < 31){
      stK0 = *(const uint4*)(gKA + (kt+1)*4096);
      stK1 = *(const uint4*)(gKB + (kt+1)*4096);
    }

    // ---- S^T = K Q^T (rows = keys, cols = q) ----
    const u16* kb = &Kl[cur][0];
    f32x16 s0, s1;
    __builtin_amdgcn_s_setprio(1);
    {
      const bf16x8 kf0 = *(const bf16x8*)(kb + fcol[0]);
      const bf16x8 kf1 = *(const bf16x8*)(kb + fcol[0] + 2048);
      s0 = __builtin_amdgcn_mfma_f32_32x32x16_bf16(kf0, qf[0], Z, 0, 0, 0);
      s1 = __builtin_amdgcn_mfma_f32_32x32x16_bf16(kf1, qf[0], Z, 0, 0, 0);
    }
    #pragma unroll
    for (int ds = 1; ds < 4; ++ds){
      const bf16x8 kf0 = *(const bf16x8*)(kb + fcol[ds]);
      const bf16x8 kf1 = *(const bf16x8*)(kb + fcol[ds] + 2048);
      s0 = __builtin_amdgcn_mfma_f32_32x32x16_bf16(kf0, qf[ds], s0, 0, 0, 0);
      s1 = __builtin_amdgcn_mfma_f32_32x32x16_bf16(kf1, qf[ds], s1, 0, 0, 0);
    }
    __builtin_amdgcn_s_setprio(0);

    // ---- P = exp2(S); row-sum (lane-local + cross-half) ----
    float rs = 0.f;
    #pragma unroll
    for (int r = 0; r < 16; ++r){
      s0[r] = __builtin_amdgcn_exp2f(s0[r]);
      s1[r] = __builtin_amdgcn_exp2f(s1[r]);
      rs += s0[r] + s1[r];
    }
    rs += __shfl_xor(rs, 32);
    ls += rs;

    // ---- pack to bf16, build PV A-frags via permlane32_swap ----
    unsigned pk[16];
    #pragma unroll
    for (int i = 0; i < 8; ++i){
      asm("v_cvt_pk_bf16_f32 %0, %1, %2" : "=v"(pk[i])   : "v"(s0[2*i]), "v"(s0[2*i+1]));
      asm("v_cvt_pk_bf16_f32 %0, %1, %2" : "=v"(pk[8+i]) : "v"(s1[2*i]), "v"(s1[2*i+1]));
    }
    bf16x8 paf[4];
    #pragma unroll
    for (int ks = 0; ks < 4; ++ks){
      const int J = 8*(ks >> 1) + 4*(ks & 1);
      unsigned a0 = pk[J+0], b0 = pk[J+2];
      unsigned a1 = pk[J+1], b1 = pk[J+3];
      asm("v_permlane32_swap_b32 %0, %1" : "+v"(a0), "+v"(b0));
      asm("v_permlane32_swap_b32 %0, %1" : "+v"(a1), "+v"(b1));
      union { unsigned u[4]; bf16x8 v; } un;
      un.u[0] = a0; un.u[1] = a1; un.u[2] = b0; un.u[3] = b1;
      paf[ks] = un.v;
    }

    // ---- O += P V ----
    __builtin_amdgcn_s_setprio(1);
    #pragma unroll
    for (int ks = 0; ks < 4; ++ks){
      accO0 = __builtin_amdgcn_mfma_f32_32x32x16_bf16(paf[ks], vf[2*ks],     accO0, 0, 0, 0);
      accO1 = __builtin_amdgcn_mfma_f32_32x32x16_bf16(paf[ks], vf[2*ks + 1], accO1, 0, 0, 0);
    }
    __builtin_amdgcn_s_setprio(0);
    cur ^= 1;
  }

  // ---- epilogue: normalize, direct stores to OT[bh][t][d] ------
  const float rl = 1.0f / ls;
  #pragma unroll
  for (int r = 0; r < 16; ++r){
    const int qr = (r & 3) + 8*(r >> 2) + 4*h;
    const float sa = __uint_as_float(
        (unsigned)__builtin_amdgcn_ds_bpermute(qr << 2, (int)__float_as_uint(rl)));
    float* dst = OT + ((size_t)bh*T_TOK + qbase + qr)*64;
    dst[c31]      = accO0[r]*sa;
    dst[32 + c31] = accO1[r]*sa;
  }
}

// ---- emit: both-sides-coalesced via LDS transpose ------------------------
__global__ __launch_bounds__(256)
void k_emit(const float* __restrict__ OT, const int* __restrict__ inv,
            float* __restrict__ out){
  __shared__ float obuf[128][68];   // [pix = y*64+x][d], pad 4
  __shared__ int invs[32];
  const int tid = threadIdx.x;
  const int pr = blockIdx.x, bh = blockIdx.y;
  const int b = bh >> 3, h = bh & 7;
  if (tid < 32) invs[tid] = inv[bh*NPATCH + pr*32 + tid];
  __syncthreads();
  const int g = tid >> 3, j = tid & 7;
  const int kk = invs[g];
  const float* tbase = OT + ((size_t)bh*T_TOK + 4*kk)*64 + j*8;
  #pragma unroll
  for (int quad = 0; quad < 4; ++quad){
    float4 v0 = {0.f,0.f,0.f,0.f}, v1 = {0.f,0.f,0.f,0.f};
    if (kk >= 0){
      v0 = *(const float4*)(tbase + quad*64);
      v1 = *(const float4*)(tbase + quad*64 + 4);
    }
    const int pix = (quad >> 1)*64 + g*2 + (quad & 1);
    *(float4*)&obuf[pix][j*8]     = v0;
    *(float4*)&obuf[pix][j*8 + 4] = v1;
  }
  __syncthreads();
  float* ob = out + ((size_t)(b*512 + h*64)*64 + 2*pr)*64;
  #pragma unroll
  for (int it = 0; it < 8; ++it){
    const int rid = it*16 + (tid >> 4);      // d*2 + y
    const int d = rid >> 1, y = rid & 1;
    const int x0 = (tid & 15)*4;
    float4 o;
    o.x = obuf[y*64 + x0 + 0][d];
    o.y = obuf[y*64 + x0 + 1][d];
    o.z = obuf[y*64 + x0 + 2][d];
    o.w = obuf[y*64 + x0 + 3][d];
    *(float4*)(ob + ((size_t)d*64 + y)*64 + x0) = o;
  }
}

extern "C" void kernel_launch(void* const* d_in, const int* in_sizes, int n_in,
                              void* d_out, int out_size, void* d_ws, size_t ws_size,
                              hipStream_t stream){
  const float* x    = (const float*)d_in[0];
  const int*   topk = (const int*)  d_in[1];
  const float* w    = (const float*)d_in[2];
  const float* bias = (const float*)d_in[3];
  float* out = (float*)d_out;
  char* ws = (char*)d_ws;

  u16*   Q   = (u16*)  (ws + WS_Q);
  u16*   K   = (u16*)  (ws + WS_K);
  u16*   Vp  = (u16*)  (ws + WS_VT);
  float* OT  = (float*)(ws + WS_OT);
  u16*   tok = (u16*)  (ws + WS_OT);   // aliases OT; dead before k_attn writes
  int*   inv = (int*)  (ws + WS_INV);

  hipMemsetAsync(inv, 0xFF, BH_N*NPATCH*sizeof(int), stream);
  k_inv <<<BH_N, 512, 0, stream>>>(topk, inv);
  k_tok <<<dim3(32, BH_N), 256, 0, stream>>>(x, inv, tok);
  k_qkv <<<dim3(8, BH_N), 256, 0, stream>>>(tok, w, bias, Q, K, Vp);
  k_attn<<<dim3(BH_N, 16), 256, 0, stream>>>(Q, K, Vp, OT);
  k_emit<<<dim3(32, BH_N), 256, 0, stream>>>(OT, inv, out);
}

// Round 9
// 145.957 us; speedup vs baseline: 1.3636x; 1.2059x over previous
//
#include <hip/hip_runtime.h>
#include <cstdint>
#include <cstddef>

// Problem constants (B=8, C=512, H=W=64, HEAD_DIM=64, PS=2)
#define T_TOK  2048   // k_sel * ps*ps tokens per (b,head)
#define NPATCH 1024
#define KSEL   512
#define BH_N   64     // B * nh

typedef unsigned short u16;
typedef __attribute__((ext_vector_type(8))) short bf16x8;   // MFMA A/B frag (4 VGPR)
typedef __attribute__((ext_vector_type(4))) float f32x4;
typedef __attribute__((ext_vector_type(16))) float f32x16;  // 32x32 MFMA C/D frag

// Workspace layout (bytes). Total = ~80.3 MiB
#define WS_Q   ((size_t)0)            // bf16 [64][2048][64]  Q (pre-scaled by 0.125*log2e)
#define WS_K   ((size_t)16 << 20)     // bf16 Kp[64][32kt][8frag][64lane][8]  (fragment-major K)
#define WS_VT  ((size_t)32 << 20)     // bf16 Vp[64][32kt][8frag][64lane][8]  (fragment-major V)
#define WS_OT  ((size_t)48 << 20)     // f32  [64][2048][64] out tokens (t-major); first 16MiB double as tok buffer
#define WS_INV ((size_t)80 << 20)     // i32  [64][1024]

static __device__ __forceinline__ u16 f2bf(float f){
  union { float f; unsigned u; } un; un.f = f;
  return (u16)((un.u + 0x7FFFu + ((un.u >> 16) & 1u)) >> 16);  // RNE
}

static __device__ __forceinline__ void gload16(const void* g, void* l){
  __builtin_amdgcn_global_load_lds(
      (const __attribute__((address_space(1))) void*)g,
      (__attribute__((address_space(3))) void*)l, 16, 0, 0);
}

// ---- inverse patch map: inv[bh][p] = selected index kk, or -1 ------------
__global__ __launch_bounds__(512)
void k_inv(const int* __restrict__ topk, int* __restrict__ inv){
  inv[blockIdx.x*NPATCH + topk[blockIdx.x*KSEL + threadIdx.x]] = threadIdx.x;
}

// ---- token build: dense layout-order read of x, write selected tokens ----
__global__ __launch_bounds__(256)
void k_tok(const float* __restrict__ x, const int* __restrict__ inv,
           u16* __restrict__ tok){
  __shared__ u16 tile[64][132];   // [d][pix]
  __shared__ int invs[32];
  const int tid = threadIdx.x;
  const int pr = blockIdx.x, bh = blockIdx.y;
  const int b = bh >> 3, h = bh & 7;
  if (tid < 32) invs[tid] = inv[bh*NPATCH + pr*32 + tid];
  const float* xb = x + ((size_t)(b*512 + h*64)*64 + 2*pr)*64;
  #pragma unroll
  for (int i = 0; i < 8; ++i){
    const int f = i*1024 + tid*4;
    const int d = f >> 7, y = (f >> 6) & 1, xx = f & 63;
    float4 v = *(const float4*)(xb + ((size_t)d*64 + y)*64 + xx);
    unsigned lo, hi;
    asm("v_cvt_pk_bf16_f32 %0, %1, %2" : "=v"(lo) : "v"(v.x), "v"(v.y));
    asm("v_cvt_pk_bf16_f32 %0, %1, %2" : "=v"(hi) : "v"(v.z), "v"(v.w));
    uint2 pk2; pk2.x = lo; pk2.y = hi;
    *(uint2*)&tile[d][y*64 + xx] = pk2;
  }
  __syncthreads();
  const int p = tid >> 3, j = tid & 7;
  const int kk = invs[p];
  if (kk >= 0){
    u16* dst = tok + ((size_t)bh*T_TOK + kk*4)*64;
    #pragma unroll
    for (int i = 0; i < 4; ++i){
      const int chunk = j*4 + i;
      const int quad = chunk >> 3, d16 = (chunk & 7)*8;
      const int pix = (quad >> 1)*64 + p*2 + (quad & 1);
      union { u16 s[8]; uint4 q; } un;
      #pragma unroll
      for (int k2 = 0; k2 < 8; ++k2) un.s[k2] = tile[d16 + k2][pix];
      *(uint4*)(dst + quad*64 + d16) = un.q;
    }
  }
}

// ---- QKV GEMM: tokens x W(192x64) -> Q(pre-scaled), Kp, Vp (frag-major) --
__global__ __launch_bounds__(256)
void k_qkv(const u16* __restrict__ tok, const float* __restrict__ w,
           const float* __restrict__ bias,
           u16* __restrict__ Q, u16* __restrict__ Kp, u16* __restrict__ Vp){
  __shared__ u16 Wl[192][72];
  __shared__ float biasl[192];
  const int tid = threadIdx.x;
  const int chunk = blockIdx.x;
  const int bh = blockIdx.y;
  for (int i2 = tid; i2 < 192*64; i2 += 256) Wl[i2 >> 6][i2 & 63] = f2bf(w[i2]);
  if (tid < 192) biasl[tid] = bias[tid];
  __syncthreads();

  const int lane = tid & 63, wv = tid >> 6;
  const int c = lane & 15, g = lane >> 4;
  const float QSC = 0.18033688f;   // 0.125 * log2(e)
  for (int tile = 0; tile < 4; ++tile){
    const int t0 = chunk*256 + tile*64;
    const int trow = t0 + wv*16 + c;
    const u16* tr = tok + ((size_t)bh*T_TOK + trow)*64;
    const bf16x8 a0 = *(const bf16x8*)(tr + 8*g);
    const bf16x8 a1 = *(const bf16x8*)(tr + 32 + 8*g);
    const int orow = t0 + wv*16 + 4*g;
    #pragma unroll
    for (int nf = 0; nf < 12; ++nf){
      const int e = nf*16 + c;
      const bf16x8 b0 = *(const bf16x8*)&Wl[e][8*g];
      const bf16x8 b1 = *(const bf16x8*)&Wl[e][32 + 8*g];
      f32x4 acc = {0.f, 0.f, 0.f, 0.f};
      acc = __builtin_amdgcn_mfma_f32_16x16x32_bf16(a0, b0, acc, 0, 0, 0);
      acc = __builtin_amdgcn_mfma_f32_16x16x32_bf16(a1, b1, acc, 0, 0, 0);
      const float bb = biasl[e];
      if (e < 64){
        u16* dst = Q + ((size_t)bh*T_TOK + orow)*64 + e;
        #pragma unroll
        for (int r2 = 0; r2 < 4; ++r2) dst[(size_t)r2*64] = f2bf((acc[r2] + bb)*QSC);
      } else if (e < 128){
        // fragment-major K: Kp[bh][kt][ds*2+rh][lane = h2*32 + key31][j]
        // value = K[key = kt*64 + rh*32 + key31][d = ds*16 + h2*8 + j]
        const int d  = e - 64;
        const int ds = d >> 4, h2 = (d >> 3) & 1, j = d & 7;
        const int kt2  = orow >> 6;
        const int key6 = orow & 63;
        const int rh = key6 >> 5, l31 = key6 & 31;
        u16* dst = Kp + ((((size_t)bh*32 + kt2)*8 + ds*2 + rh)*64 + (h2*32 + l31))*8 + j;
        #pragma unroll
        for (int r2 = 0; r2 < 4; ++r2) dst[r2*8] = f2bf(acc[r2] + bb);
      } else {
        // fragment-major V: Vp[bh][kt][ks*2+C][lane = h2*32 + d31][j]
        // value = V[key][d], frag (ks,C): lane holds V[16ks+8h2+j][C*32+d31]
        const int d  = e - 128;
        const int C  = d >> 5, dp = d & 31;
        const int kt2 = orow >> 6, key = orow & 63;
        const int ks = key >> 4, h2 = (key >> 3) & 1, j0 = key & 7; // j0 in {0,4}
        u16* dst = Vp + ((((size_t)bh*32 + kt2)*8 + ks*2 + C)*64 + (h2*32 + dp))*8 + j0;
        unsigned u01 = (unsigned)f2bf(acc[0] + bb) | ((unsigned)f2bf(acc[1] + bb) << 16);
        unsigned u23 = (unsigned)f2bf(acc[2] + bb) | ((unsigned)f2bf(acc[3] + bb) << 16);
        *(unsigned*)(dst)     = u01;
        *(unsigned*)(dst + 2) = u23;
      }
    }
  }
}

// ---- flash attention: 4 waves x 32 q-rows, 4 blocks/CU -------------------
// K,V tiles DMA'd (global_load_lds) from fragment-major buffers; every LDS
// fragment read is base + lane*16B (conflict-free, zero addr VALU).
// No-max softmax (exact: Q pre-scaled by 0.125*log2e, logits tiny).
__global__ __launch_bounds__(256, 4)
void k_attn(const u16* __restrict__ Q, const u16* __restrict__ Kp,
            const u16* __restrict__ Vp, float* __restrict__ OT){
  __shared__ u16 KVl[2][8192];   // per buf: 8 K frags [64][8] + 8 V frags
  const int tid = threadIdx.x;
  const int bh = blockIdx.x, qt = blockIdx.y;   // bh-major: qt blocks share one XCD's L2
  const int l = tid & 63, w = tid >> 6;
  const int h = l >> 5, c31 = l & 31;
  const int qbase = qt*128 + w*32;

  // Q fragments (B-operand)
  bf16x8 qf[4];
  {
    const u16* qr = Q + ((size_t)bh*T_TOK + qbase + c31)*64;
    #pragma unroll
    for (int kd = 0; kd < 4; ++kd) qf[kd] = *(const bf16x8*)(qr + kd*16 + 8*h);
  }

  f32x16 Z;
  #pragma unroll
  for (int r = 0; r < 16; ++r) Z[r] = 0.f;
  f32x16 accO0 = Z, accO1 = Z;
  float ls = 0.f;

  const u16* gKt = Kp + (size_t)bh*131072;   // 32 tiles x 4096 u16
  const u16* gVt = Vp + (size_t)bh*131072;

  // prologue: DMA tile 0 into buffer 0
  {
    u16* ld = &KVl[0][0] + tid*8;
    gload16(gKt + tid*8,        ld);
    gload16(gKt + 2048 + tid*8, ld + 2048);
    gload16(gVt + tid*8,        ld + 4096);
    gload16(gVt + 2048 + tid*8, ld + 6144);
  }
  __syncthreads();

  int cur = 0;
  for (int kt = 0; kt < 32; ++kt){
    if (kt < 31){   // DMA next tile into the other buffer
      const u16* sk = gKt + (kt + 1)*4096 + tid*8;
      const u16* sv = gVt + (kt + 1)*4096 + tid*8;
      u16* ld = &KVl[cur ^ 1][0] + tid*8;
      gload16(sk,        ld);
      gload16(sk + 2048, ld + 2048);
      gload16(sv,        ld + 4096);
      gload16(sv + 2048, ld + 6144);
    }

    const u16* kb = &KVl[cur][l*8];   // frag f at byte offset f*1024

    // ---- S^T = K Q^T (rows = keys, cols = q) ----
    f32x16 s0, s1;
    __builtin_amdgcn_s_setprio(1);
    s0 = __builtin_amdgcn_mfma_f32_32x32x16_bf16(*(const bf16x8*)(kb),       qf[0], Z, 0, 0, 0);
    s1 = __builtin_amdgcn_mfma_f32_32x32x16_bf16(*(const bf16x8*)(kb + 512), qf[0], Z, 0, 0, 0);
    #pragma unroll
    for (int ds = 1; ds < 4; ++ds){
      s0 = __builtin_amdgcn_mfma_f32_32x32x16_bf16(*(const bf16x8*)(kb + ds*1024),       qf[ds], s0, 0, 0, 0);
      s1 = __builtin_amdgcn_mfma_f32_32x32x16_bf16(*(const bf16x8*)(kb + ds*1024 + 512), qf[ds], s1, 0, 0, 0);
    }
    __builtin_amdgcn_s_setprio(0);

    // ---- P = exp2(S); row-sum (lane-local + cross-half) ----
    float rs = 0.f;
    #pragma unroll
    for (int r = 0; r < 16; ++r){
      s0[r] = __builtin_amdgcn_exp2f(s0[r]);
      s1[r] = __builtin_amdgcn_exp2f(s1[r]);
      rs += s0[r] + s1[r];
    }
    rs += __shfl_xor(rs, 32);
    ls += rs;

    // ---- pack to bf16, build PV A-frags via permlane32_swap ----
    unsigned pk[16];
    #pragma unroll
    for (int i = 0; i < 8; ++i){
      asm("v_cvt_pk_bf16_f32 %0, %1, %2" : "=v"(pk[i])   : "v"(s0[2*i]), "v"(s0[2*i+1]));
      asm("v_cvt_pk_bf16_f32 %0, %1, %2" : "=v"(pk[8+i]) : "v"(s1[2*i]), "v"(s1[2*i+1]));
    }
    bf16x8 paf[4];
    #pragma unroll
    for (int ks = 0; ks < 4; ++ks){
      const int J = 8*(ks >> 1) + 4*(ks & 1);
      unsigned a0 = pk[J+0], b0 = pk[J+2];
      unsigned a1 = pk[J+1], b1 = pk[J+3];
      asm("v_permlane32_swap_b32 %0, %1" : "+v"(a0), "+v"(b0));
      asm("v_permlane32_swap_b32 %0, %1" : "+v"(a1), "+v"(b1));
      union { unsigned u[4]; bf16x8 v; } un;
      un.u[0] = a0; un.u[1] = a1; un.u[2] = b0; un.u[3] = b1;
      paf[ks] = un.v;
    }

    // ---- O += P V ----
    const u16* vb = kb + 4096;
    __builtin_amdgcn_s_setprio(1);
    #pragma unroll
    for (int ks = 0; ks < 4; ++ks){
      accO0 = __builtin_amdgcn_mfma_f32_32x32x16_bf16(paf[ks], *(const bf16x8*)(vb + ks*1024),       accO0, 0, 0, 0);
      accO1 = __builtin_amdgcn_mfma_f32_32x32x16_bf16(paf[ks], *(const bf16x8*)(vb + ks*1024 + 512), accO1, 0, 0, 0);
    }
    __builtin_amdgcn_s_setprio(0);

    __syncthreads();   // drains next-tile DMA (vmcnt) + buffer-swap safety
    cur ^= 1;
  }

  // ---- epilogue: normalize, direct stores to OT[bh][t][d] ------
  const float rl = 1.0f / ls;
  #pragma unroll
  for (int r = 0; r < 16; ++r){
    const int qr = (r & 3) + 8*(r >> 2) + 4*h;
    const float sa = __uint_as_float(
        (unsigned)__builtin_amdgcn_ds_bpermute(qr << 2, (int)__float_as_uint(rl)));
    float* dst = OT + ((size_t)bh*T_TOK + qbase + qr)*64;
    dst[c31]      = accO0[r]*sa;
    dst[32 + c31] = accO1[r]*sa;
  }
}

// ---- emit: both-sides-coalesced via LDS transpose ------------------------
__global__ __launch_bounds__(256)
void k_emit(const float* __restrict__ OT, const int* __restrict__ inv,
            float* __restrict__ out){
  __shared__ float obuf[128][68];   // [pix = y*64+x][d], pad 4
  __shared__ int invs[32];
  const int tid = threadIdx.x;
  const int pr = blockIdx.x, bh = blockIdx.y;
  const int b = bh >> 3, h = bh & 7;
  if (tid < 32) invs[tid] = inv[bh*NPATCH + pr*32 + tid];
  __syncthreads();
  const int g = tid >> 3, j = tid & 7;
  const int kk = invs[g];
  const float* tbase = OT + ((size_t)bh*T_TOK + 4*kk)*64 + j*8;
  #pragma unroll
  for (int quad = 0; quad < 4; ++quad){
    float4 v0 = {0.f,0.f,0.f,0.f}, v1 = {0.f,0.f,0.f,0.f};
    if (kk >= 0){
      v0 = *(const float4*)(tbase + quad*64);
      v1 = *(const float4*)(tbase + quad*64 + 4);
    }
    const int pix = (quad >> 1)*64 + g*2 + (quad & 1);
    *(float4*)&obuf[pix][j*8]     = v0;
    *(float4*)&obuf[pix][j*8 + 4] = v1;
  }
  __syncthreads();
  float* ob = out + ((size_t)(b*512 + h*64)*64 + 2*pr)*64;
  #pragma unroll
  for (int it = 0; it < 8; ++it){
    const int rid = it*16 + (tid >> 4);      // d*2 + y
    const int d = rid >> 1, y = rid & 1;
    const int x0 = (tid & 15)*4;
    float4 o;
    o.x = obuf[y*64 + x0 + 0][d];
    o.y = obuf[y*64 + x0 + 1][d];
    o.z = obuf[y*64 + x0 + 2][d];
    o.w = obuf[y*64 + x0 + 3][d];
    *(float4*)(ob + ((size_t)d*64 + y)*64 + x0) = o;
  }
}

extern "C" void kernel_launch(void* const* d_in, const int* in_sizes, int n_in,
                              void* d_out, int out_size, void* d_ws, size_t ws_size,
                              hipStream_t stream){
  const float* x    = (const float*)d_in[0];
  const int*   topk = (const int*)  d_in[1];
  const float* w    = (const float*)d_in[2];
  const float* bias = (const float*)d_in[3];
  float* out = (float*)d_out;
  char* ws = (char*)d_ws;

  u16*   Q   = (u16*)  (ws + WS_Q);
  u16*   Kp  = (u16*)  (ws + WS_K);
  u16*   Vp  = (u16*)  (ws + WS_VT);
  float* OT  = (float*)(ws + WS_OT);
  u16*   tok = (u16*)  (ws + WS_OT);   // aliases OT; dead before k_attn writes
  int*   inv = (int*)  (ws + WS_INV);

  hipMemsetAsync(inv, 0xFF, BH_N*NPATCH*sizeof(int), stream);
  k_inv <<<BH_N, 512, 0, stream>>>(topk, inv);
  k_tok <<<dim3(32, BH_N), 256, 0, stream>>>(x, inv, tok);
  k_qkv <<<dim3(8, BH_N), 256, 0, stream>>>(tok, w, bias, Q, Kp, Vp);
  k_attn<<<dim3(BH_N, 16), 256, 0, stream>>>(Q, Kp, Vp, OT);
  k_emit<<<dim3(32, BH_N), 256, 0, stream>>>(OT, inv, out);
}

// Round 10
// 144.804 us; speedup vs baseline: 1.3745x; 1.0080x over previous
//
#include <hip/hip_runtime.h>
#include <cstdint>
#include <cstddef>

// Problem constants (B=8, C=512, H=W=64, HEAD_DIM=64, PS=2)
#define T_TOK  2048   // k_sel * ps*ps tokens per (b,head)
#define NPATCH 1024
#define KSEL   512
#define BH_N   64     // B * nh

typedef unsigned short u16;
typedef __attribute__((ext_vector_type(8))) short bf16x8;   // MFMA A/B frag (4 VGPR)
typedef __attribute__((ext_vector_type(4))) float f32x4;
typedef __attribute__((ext_vector_type(16))) float f32x16;  // 32x32 MFMA C/D frag

// Workspace layout (bytes). Total = ~80.3 MiB
#define WS_Q   ((size_t)0)            // bf16 Qp[64][64 g32][4 kd][64 lane][8] (frag-major Q, pre-scaled)
#define WS_K   ((size_t)16 << 20)     // bf16 Kp[64][32kt][8frag][64lane][8]  (fragment-major K)
#define WS_VT  ((size_t)32 << 20)     // bf16 Vp[64][32kt][8frag][64lane][8]  (fragment-major V)
#define WS_OT  ((size_t)48 << 20)     // f32  [64][2048][64] out tokens (t-major); first 16MiB double as tok buffer
#define WS_INV ((size_t)80 << 20)     // i32  [64][1024]

static __device__ __forceinline__ u16 f2bf(float f){
  union { float f; unsigned u; } un; un.f = f;
  return (u16)((un.u + 0x7FFFu + ((un.u >> 16) & 1u)) >> 16);  // RNE
}

static __device__ __forceinline__ void gload16(const void* g, void* l){
  __builtin_amdgcn_global_load_lds(
      (const __attribute__((address_space(1))) void*)g,
      (__attribute__((address_space(3))) void*)l, 16, 0, 0);
}

// ---- inverse patch map: inv[bh][p] = selected index kk, or -1 ------------
__global__ __launch_bounds__(512)
void k_inv(const int* __restrict__ topk, int* __restrict__ inv){
  inv[blockIdx.x*NPATCH + topk[blockIdx.x*KSEL + threadIdx.x]] = threadIdx.x;
}

// ---- token build: dense layout-order read of x, write selected tokens ----
__global__ __launch_bounds__(256)
void k_tok(const float* __restrict__ x, const int* __restrict__ inv,
           u16* __restrict__ tok){
  __shared__ u16 tile[64][132];   // [d][pix]
  __shared__ int invs[32];
  const int tid = threadIdx.x;
  const int pr = blockIdx.x, bh = blockIdx.y;
  const int b = bh >> 3, h = bh & 7;
  if (tid < 32) invs[tid] = inv[bh*NPATCH + pr*32 + tid];
  const float* xb = x + ((size_t)(b*512 + h*64)*64 + 2*pr)*64;
  #pragma unroll
  for (int i = 0; i < 8; ++i){
    const int f = i*1024 + tid*4;
    const int d = f >> 7, y = (f >> 6) & 1, xx = f & 63;
    float4 v = *(const float4*)(xb + ((size_t)d*64 + y)*64 + xx);
    unsigned lo, hi;
    asm("v_cvt_pk_bf16_f32 %0, %1, %2" : "=v"(lo) : "v"(v.x), "v"(v.y));
    asm("v_cvt_pk_bf16_f32 %0, %1, %2" : "=v"(hi) : "v"(v.z), "v"(v.w));
    uint2 pk2; pk2.x = lo; pk2.y = hi;
    *(uint2*)&tile[d][y*64 + xx] = pk2;
  }
  __syncthreads();
  const int p = tid >> 3, j = tid & 7;
  const int kk = invs[p];
  if (kk >= 0){
    u16* dst = tok + ((size_t)bh*T_TOK + kk*4)*64;
    #pragma unroll
    for (int i = 0; i < 4; ++i){
      const int chunk = j*4 + i;
      const int quad = chunk >> 3, d16 = (chunk & 7)*8;
      const int pix = (quad >> 1)*64 + p*2 + (quad & 1);
      union { u16 s[8]; uint4 q; } un;
      #pragma unroll
      for (int k2 = 0; k2 < 8; ++k2) un.s[k2] = tile[d16 + k2][pix];
      *(uint4*)(dst + quad*64 + d16) = un.q;
    }
  }
}

// ---- QKV GEMM: tokens x W -> Qp, Kp, Vp (all frag-major, coalesced) ------
__global__ __launch_bounds__(256)
void k_qkv(const u16* __restrict__ tok, const float* __restrict__ w,
           const float* __restrict__ bias,
           u16* __restrict__ Qp, u16* __restrict__ Kp, u16* __restrict__ Vp){
  __shared__ u16 Wl[192][72];
  __shared__ float biasl[192];
  __shared__ u16 Tq[64][72];   // [q][d]
  __shared__ u16 Tk[64][72];   // [key][d]
  __shared__ u16 Tv[64][72];   // [d][key]  (transposed for b128 frag reads)
  const int tid = threadIdx.x;
  const int chunk = blockIdx.x;
  const int bh = blockIdx.y;
  for (int i2 = tid; i2 < 192*64; i2 += 256) Wl[i2 >> 6][i2 & 63] = f2bf(w[i2]);
  if (tid < 192) biasl[tid] = bias[tid];
  __syncthreads();

  const int lane = tid & 63, wv = tid >> 6;
  const int c = lane & 15, g = lane >> 4;
  const float QSC = 0.18033688f;   // 0.125 * log2(e)
  for (int tile = 0; tile < 4; ++tile){
    const int t0 = chunk*256 + tile*64;
    const int kt2 = t0 >> 6;
    const int trow = t0 + wv*16 + c;
    const u16* tr = tok + ((size_t)bh*T_TOK + trow)*64;
    const bf16x8 a0 = *(const bf16x8*)(tr + 8*g);
    const bf16x8 a1 = *(const bf16x8*)(tr + 32 + 8*g);
    const int lr = wv*16 + 4*g;           // local output row base (0..60)
    #pragma unroll
    for (int nf = 0; nf < 12; ++nf){
      const int e = nf*16 + c;
      const bf16x8 b0 = *(const bf16x8*)&Wl[e][8*g];
      const bf16x8 b1 = *(const bf16x8*)&Wl[e][32 + 8*g];
      f32x4 acc = {0.f, 0.f, 0.f, 0.f};
      acc = __builtin_amdgcn_mfma_f32_16x16x32_bf16(a0, b0, acc, 0, 0, 0);
      acc = __builtin_amdgcn_mfma_f32_16x16x32_bf16(a1, b1, acc, 0, 0, 0);
      const float bb = biasl[e];
      if (e < 64){
        #pragma unroll
        for (int r2 = 0; r2 < 4; ++r2) Tq[lr + r2][e] = f2bf((acc[r2] + bb)*QSC);
      } else if (e < 128){
        #pragma unroll
        for (int r2 = 0; r2 < 4; ++r2) Tk[lr + r2][e - 64] = f2bf(acc[r2] + bb);
      } else {
        // Tv[d][key]: 4 consecutive keys -> one 8B write
        unsigned u01 = (unsigned)f2bf(acc[0] + bb) | ((unsigned)f2bf(acc[1] + bb) << 16);
        unsigned u23 = (unsigned)f2bf(acc[2] + bb) | ((unsigned)f2bf(acc[3] + bb) << 16);
        uint2 pk2; pk2.x = u01; pk2.y = u23;
        *(uint2*)&Tv[e - 128][lr] = pk2;
      }
    }
    __syncthreads();
    // coalesced frag-major stores: thread -> two 16B slots per tensor
    #pragma unroll
    for (int c2 = 0; c2 < 2; ++c2){
      const int s  = tid*2 + c2;        // 0..511
      const int ls = s & 63, f = s >> 6;
      const int r31 = ls & 31, h2 = ls >> 5;
      // Q: f = g2*4 + kd
      {
        const int g2 = f >> 2, kd = f & 3;
        const bf16x8 v = *(const bf16x8*)&Tq[g2*32 + r31][kd*16 + h2*8];
        *(bf16x8*)(Qp + (size_t)bh*131072 + ((size_t)((t0 >> 5) + g2)*4 + kd)*512 + ls*8) = v;
      }
      // K: f = ds*2 + rh
      {
        const int ds = f >> 1, rh = f & 1;
        const bf16x8 v = *(const bf16x8*)&Tk[rh*32 + r31][ds*16 + h2*8];
        *(bf16x8*)(Kp + (((size_t)bh*32 + kt2)*8 + f)*512 + ls*8) = v;
      }
      // V: f = ks*2 + C
      {
        const int ks = f >> 1, C = f & 1;
        const bf16x8 v = *(const bf16x8*)&Tv[C*32 + r31][ks*16 + h2*8];
        *(bf16x8*)(Vp + (((size_t)bh*32 + kt2)*8 + f)*512 + ls*8) = v;
      }
    }
    __syncthreads();
  }
}

// ---- flash attention: 4 waves x 32 q-rows, 4 blocks/CU -------------------
// Frag-major K/V DMA'd to LDS (conflict-free reads). Stage-interleaved body:
// QK(s0,s1) -> SM(s0) -> PV(ks0,1) -> SM(s1) -> PV(ks2,3) so VALU/trans of
// one half-stream runs under the MFMA shadow of the other.
__global__ __launch_bounds__(256, 4)
void k_attn(const u16* __restrict__ Qp, const u16* __restrict__ Kp,
            const u16* __restrict__ Vp, float* __restrict__ OT){
  __shared__ u16 KVl[2][8192];   // per buf: 8 K frags [64][8] + 8 V frags
  const int tid = threadIdx.x;
  const int bh = blockIdx.x, qt = blockIdx.y;   // bh-major: qt blocks share one XCD's L2
  const int l = tid & 63, w = tid >> 6;
  const int h = l >> 5, c31 = l & 31;
  const int qbase = qt*128 + w*32;

  // Q fragments: frag-major, coalesced 16B/lane
  bf16x8 qf[4];
  {
    const u16* qpb = Qp + (size_t)bh*131072 + ((size_t)(qt*4 + w)*4)*512 + l*8;
    #pragma unroll
    for (int kd = 0; kd < 4; ++kd) qf[kd] = *(const bf16x8*)(qpb + kd*512);
  }

  f32x16 Z;
  #pragma unroll
  for (int r = 0; r < 16; ++r) Z[r] = 0.f;
  f32x16 accO0 = Z, accO1 = Z;
  float ls = 0.f;

  const u16* gKt = Kp + (size_t)bh*131072;   // 32 tiles x 4096 u16
  const u16* gVt = Vp + (size_t)bh*131072;

  // prologue: DMA tile 0 into buffer 0
  {
    u16* ld = &KVl[0][0] + tid*8;
    gload16(gKt + tid*8,        ld);
    gload16(gKt + 2048 + tid*8, ld + 2048);
    gload16(gVt + tid*8,        ld + 4096);
    gload16(gVt + 2048 + tid*8, ld + 6144);
  }
  __syncthreads();

  int cur = 0;
  for (int kt = 0; kt < 32; ++kt){
    if (kt < 31){   // DMA next tile into the other buffer (drained by end barrier)
      const u16* sk = gKt + (kt + 1)*4096 + tid*8;
      const u16* sv = gVt + (kt + 1)*4096 + tid*8;
      u16* ld = &KVl[cur ^ 1][0] + tid*8;
      gload16(sk,        ld);
      gload16(sk + 2048, ld + 2048);
      gload16(sv,        ld + 4096);
      gload16(sv + 2048, ld + 6144);
    }

    const u16* kb = &KVl[cur][l*8];   // frag f at u16 offset f*512
    const u16* vb = kb + 4096;

    // ---- QK: s0 chain (keys 0..31), then s1 chain (keys 32..63) ----
    f32x16 s0, s1;
    __builtin_amdgcn_s_setprio(1);
    s0 = __builtin_amdgcn_mfma_f32_32x32x16_bf16(*(const bf16x8*)(kb),        qf[0], Z,  0, 0, 0);
    s0 = __builtin_amdgcn_mfma_f32_32x32x16_bf16(*(const bf16x8*)(kb + 1024), qf[1], s0, 0, 0, 0);
    s0 = __builtin_amdgcn_mfma_f32_32x32x16_bf16(*(const bf16x8*)(kb + 2048), qf[2], s0, 0, 0, 0);
    s0 = __builtin_amdgcn_mfma_f32_32x32x16_bf16(*(const bf16x8*)(kb + 3072), qf[3], s0, 0, 0, 0);
    s1 = __builtin_amdgcn_mfma_f32_32x32x16_bf16(*(const bf16x8*)(kb + 512),  qf[0], Z,  0, 0, 0);
    s1 = __builtin_amdgcn_mfma_f32_32x32x16_bf16(*(const bf16x8*)(kb + 1536), qf[1], s1, 0, 0, 0);
    s1 = __builtin_amdgcn_mfma_f32_32x32x16_bf16(*(const bf16x8*)(kb + 2560), qf[2], s1, 0, 0, 0);
    s1 = __builtin_amdgcn_mfma_f32_32x32x16_bf16(*(const bf16x8*)(kb + 3584), qf[3], s1, 0, 0, 0);
    __builtin_amdgcn_s_setprio(0);

    // ---- SM(s0): exp2 + pack -> paf0, paf1 (independent of s1 MFMA tail) --
    float rs = 0.f;
    #pragma unroll
    for (int r = 0; r < 16; ++r){ s0[r] = __builtin_amdgcn_exp2f(s0[r]); rs += s0[r]; }
    unsigned pk0[8];
    #pragma unroll
    for (int i = 0; i < 8; ++i)
      asm("v_cvt_pk_bf16_f32 %0, %1, %2" : "=v"(pk0[i]) : "v"(s0[2*i]), "v"(s0[2*i+1]));
    bf16x8 paf0, paf1;
    {
      unsigned a0 = pk0[0], b0 = pk0[2], a1 = pk0[1], b1 = pk0[3];
      asm("v_permlane32_swap_b32 %0, %1" : "+v"(a0), "+v"(b0));
      asm("v_permlane32_swap_b32 %0, %1" : "+v"(a1), "+v"(b1));
      union { unsigned u[4]; bf16x8 v; } un;
      un.u[0] = a0; un.u[1] = a1; un.u[2] = b0; un.u[3] = b1;
      paf0 = un.v;
      unsigned c0 = pk0[4], d0 = pk0[6], c1 = pk0[5], d1 = pk0[7];
      asm("v_permlane32_swap_b32 %0, %1" : "+v"(c0), "+v"(d0));
      asm("v_permlane32_swap_b32 %0, %1" : "+v"(c1), "+v"(d1));
      union { unsigned u[4]; bf16x8 v; } un2;
      un2.u[0] = c0; un2.u[1] = c1; un2.u[2] = d0; un2.u[3] = d1;
      paf1 = un2.v;
    }

    // ---- PV ks=0,1 (runs while SM(s1) VALU issues) ----
    __builtin_amdgcn_s_setprio(1);
    accO0 = __builtin_amdgcn_mfma_f32_32x32x16_bf16(paf0, *(const bf16x8*)(vb),        accO0, 0, 0, 0);
    accO1 = __builtin_amdgcn_mfma_f32_32x32x16_bf16(paf0, *(const bf16x8*)(vb + 512),  accO1, 0, 0, 0);
    accO0 = __builtin_amdgcn_mfma_f32_32x32x16_bf16(paf1, *(const bf16x8*)(vb + 1024), accO0, 0, 0, 0);
    accO1 = __builtin_amdgcn_mfma_f32_32x32x16_bf16(paf1, *(const bf16x8*)(vb + 1536), accO1, 0, 0, 0);
    __builtin_amdgcn_s_setprio(0);

    // ---- SM(s1) ----
    #pragma unroll
    for (int r = 0; r < 16; ++r){ s1[r] = __builtin_amdgcn_exp2f(s1[r]); rs += s1[r]; }
    unsigned pk1[8];
    #pragma unroll
    for (int i = 0; i < 8; ++i)
      asm("v_cvt_pk_bf16_f32 %0, %1, %2" : "=v"(pk1[i]) : "v"(s1[2*i]), "v"(s1[2*i+1]));
    bf16x8 paf2, paf3;
    {
      unsigned a0 = pk1[0], b0 = pk1[2], a1 = pk1[1], b1 = pk1[3];
      asm("v_permlane32_swap_b32 %0, %1" : "+v"(a0), "+v"(b0));
      asm("v_permlane32_swap_b32 %0, %1" : "+v"(a1), "+v"(b1));
      union { unsigned u[4]; bf16x8 v; } un;
      un.u[0] = a0; un.u[1] = a1; un.u[2] = b0; un.u[3] = b1;
      paf2 = un.v;
      unsigned c0 = pk1[4], d0 = pk1[6], c1 = pk1[5], d1 = pk1[7];
      asm("v_permlane32_swap_b32 %0, %1" : "+v"(c0), "+v"(d0));
      asm("v_permlane32_swap_b32 %0, %1" : "+v"(c1), "+v"(d1));
      union { unsigned u[4]; bf16x8 v; } un2;
      un2.u[0] = c0; un2.u[1] = c1; un2.u[2] = d0; un2.u[3] = d1;
      paf3 = un2.v;
    }

    // ---- PV ks=2,3 ----
    __builtin_amdgcn_s_setprio(1);
    accO0 = __builtin_amdgcn_mfma_f32_32x32x16_bf16(paf2, *(const bf16x8*)(vb + 2048), accO0, 0, 0, 0);
    accO1 = __builtin_amdgcn_mfma_f32_32x32x16_bf16(paf2, *(const bf16x8*)(vb + 2560), accO1, 0, 0, 0);
    accO0 = __builtin_amdgcn_mfma_f32_32x32x16_bf16(paf3, *(const bf16x8*)(vb + 3072), accO0, 0, 0, 0);
    accO1 = __builtin_amdgcn_mfma_f32_32x32x16_bf16(paf3, *(const bf16x8*)(vb + 3584), accO1, 0, 0, 0);
    __builtin_amdgcn_s_setprio(0);

    // ---- row-sum tail ----
    rs += __shfl_xor(rs, 32);
    ls += rs;

    __syncthreads();   // drains next-tile DMA + buffer-swap safety
    cur ^= 1;
  }

  // ---- epilogue: normalize, direct stores to OT[bh][t][d] ------
  const float rl = 1.0f / ls;
  #pragma unroll
  for (int r = 0; r < 16; ++r){
    const int qr = (r & 3) + 8*(r >> 2) + 4*h;
    const float sa = __uint_as_float(
        (unsigned)__builtin_amdgcn_ds_bpermute(qr << 2, (int)__float_as_uint(rl)));
    float* dst = OT + ((size_t)bh*T_TOK + qbase + qr)*64;
    dst[c31]      = accO0[r]*sa;
    dst[32 + c31] = accO1[r]*sa;
  }
}

// ---- emit: both-sides-coalesced via LDS transpose ------------------------
__global__ __launch_bounds__(256)
void k_emit(const float* __restrict__ OT, const int* __restrict__ inv,
            float* __restrict__ out){
  __shared__ float obuf[128][68];   // [pix = y*64+x][d], pad 4
  __shared__ int invs[32];
  const int tid = threadIdx.x;
  const int pr = blockIdx.x, bh = blockIdx.y;
  const int b = bh >> 3, h = bh & 7;
  if (tid < 32) invs[tid] = inv[bh*NPATCH + pr*32 + tid];
  __syncthreads();
  const int g = tid >> 3, j = tid & 7;
  const int kk = invs[g];
  const float* tbase = OT + ((size_t)bh*T_TOK + 4*kk)*64 + j*8;
  #pragma unroll
  for (int quad = 0; quad < 4; ++quad){
    float4 v0 = {0.f,0.f,0.f,0.f}, v1 = {0.f,0.f,0.f,0.f};
    if (kk >= 0){
      v0 = *(const float4*)(tbase + quad*64);
      v1 = *(const float4*)(tbase + quad*64 + 4);
    }
    const int pix = (quad >> 1)*64 + g*2 + (quad & 1);
    *(float4*)&obuf[pix][j*8]     = v0;
    *(float4*)&obuf[pix][j*8 + 4] = v1;
  }
  __syncthreads();
  float* ob = out + ((size_t)(b*512 + h*64)*64 + 2*pr)*64;
  #pragma unroll
  for (int it = 0; it < 8; ++it){
    const int rid = it*16 + (tid >> 4);      // d*2 + y
    const int d = rid >> 1, y = rid & 1;
    const int x0 = (tid & 15)*4;
    float4 o;
    o.x = obuf[y*64 + x0 + 0][d];
    o.y = obuf[y*64 + x0 + 1][d];
    o.z = obuf[y*64 + x0 + 2][d];
    o.w = obuf[y*64 + x0 + 3][d];
    *(float4*)(ob + ((size_t)d*64 + y)*64 + x0) = o;
  }
}

extern "C" void kernel_launch(void* const* d_in, const int* in_sizes, int n_in,
                              void* d_out, int out_size, void* d_ws, size_t ws_size,
                              hipStream_t stream){
  const float* x    = (const float*)d_in[0];
  const int*   topk = (const int*)  d_in[1];
  const float* w    = (const float*)d_in[2];
  const float* bias = (const float*)d_in[3];
  float* out = (float*)d_out;
  char* ws = (char*)d_ws;

  u16*   Qp  = (u16*)  (ws + WS_Q);
  u16*   Kp  = (u16*)  (ws + WS_K);
  u16*   Vp  = (u16*)  (ws + WS_VT);
  float* OT  = (float*)(ws + WS_OT);
  u16*   tok = (u16*)  (ws + WS_OT);   // aliases OT; dead before k_attn writes
  int*   inv = (int*)  (ws + WS_INV);

  hipMemsetAsync(inv, 0xFF, BH_N*NPATCH*sizeof(int), stream);
  k_inv <<<BH_N, 512, 0, stream>>>(topk, inv);
  k_tok <<<dim3(32, BH_N), 256, 0, stream>>>(x, inv, tok);
  k_qkv <<<dim3(8, BH_N), 256, 0, stream>>>(tok, w, bias, Qp, Kp, Vp);
  k_attn<<<dim3(BH_N, 16), 256, 0, stream>>>(Qp, Kp, Vp, OT);
  k_emit<<<dim3(32, BH_N), 256, 0, stream>>>(OT, inv, out);
}